// Round 1
// baseline (58.695 us; speedup 1.0000x reference)
//
#include <hip/hip_runtime.h>
#include <hip/hip_bf16.h>

// int4-dequant GEMM, M=32 (last token), K=4096, N=32000 (of 32064 padded).
// qweight [K][16032] int32 (one byte/word: lo nibble = even col, hi = odd col)
// w[k][n] = (q - z) * s, group g = k/128.
//
// Strategy: f16 MFMA (16x16x32), fp32 accumulate. A pre-packed to fragment
// layout in d_ws by prep kernel using k-bijection kappa(h,j) = 8h+j; B built
// with the same kappa, so the result is independent of HW's internal k order.
// Grid: 500 N-tiles x 64 cols; 8 waves/block split K (512 rows each), LDS
// tree-reduction at the end. qweight read straight from global (L1 catches
// the 4x intra-kstep reuse of each 128B row slice).

typedef _Float16 f16x8 __attribute__((ext_vector_type(8)));
typedef float f32x4 __attribute__((ext_vector_type(4)));

#define K_DIM 4096
#define NP 16032       // packed words per row
#define NSC 32064      // scales row pitch
#define NOUT 32000
#define S_LEN 64

// ---- pre-kernel: pack x[:,63,:] (f32) into A fragments (f16) ----
// layout: aws[(kstep*2 + mblk)*64 + lane][j] , j=0..7
//   holds A[m][k], m = mblk*16 + (lane&15), k = kstep*32 + 8*(lane>>4) + j
__global__ void prep_a_kernel(const float* __restrict__ x,
                              _Float16* __restrict__ aws) {
    int tid = blockIdx.x * 256 + threadIdx.x;   // 0..16383
    int l = tid & 63;
    int mblk = (tid >> 6) & 1;
    int ks = tid >> 7;                          // kstep 0..127
    int m = mblk * 16 + (l & 15);
    int kbase = ks * 32 + 8 * (l >> 4);
    const float* xp = x + (size_t)m * S_LEN * K_DIM + (size_t)(S_LEN - 1) * K_DIM + kbase;
    _Float16* op = aws + (size_t)tid * 8;
#pragma unroll
    for (int j = 0; j < 8; ++j) op[j] = (_Float16)xp[j];
}

// ---- main kernel ----
__global__ __launch_bounds__(512)
void q4gemm_kernel(const int* __restrict__ qw,
                   const float* __restrict__ scales,
                   const int* __restrict__ qzeros,
                   const float* __restrict__ bias,
                   const _Float16* __restrict__ aws,
                   float* __restrict__ out) {
    __shared__ float red[8 * 2048];   // 64 KB: per-wave partial C tiles

    const int tid = threadIdx.x;
    const int w = tid >> 6;          // wave 0..7 (K-chunk owner)
    const int l = tid & 63;
    const int h = l >> 4;            // k lane-group 0..3
    const int c = l & 15;            // column within 16-wide subtile
    const int hw = c >> 1;           // packed-word offset within subtile
    const int sh = (l & 1) * 4;      // nibble shift for this column
    const int n0 = blockIdx.x * 64;  // 64 output cols per block
    const int np0 = n0 >> 1;         // 32 packed words per block

    f32x4 acc[2][4] = {};            // [mblk][sub]
    float sv[4], zs[4];

    for (int t = 0; t < 16; ++t) {
        const int ks_g = w * 16 + t;       // global kstep
        const int k0 = ks_g * 32;

        if ((t & 3) == 0) {                // new 128-row quant group
            const int g = k0 >> 7;
#pragma unroll
            for (int sub = 0; sub < 4; ++sub) {
                float s = scales[(size_t)g * NSC + n0 + sub * 16 + c];
                int zq = (qzeros[(size_t)g * NP + np0 + sub * 8 + hw] >> sh) & 15;
                sv[sub] = s;
                zs[sub] = (float)zq * s;
            }
        }

        // A fragments (L2/L3-hot after first pass)
        f16x8 a0 = *(const f16x8*)(aws + ((size_t)(ks_g * 2 + 0) * 64 + l) * 8);
        f16x8 a1 = *(const f16x8*)(aws + ((size_t)(ks_g * 2 + 1) * 64 + l) * 8);

#pragma unroll
        for (int sub = 0; sub < 4; ++sub) {
            int qrow[8];
#pragma unroll
            for (int j = 0; j < 8; ++j) {
                const int* rp = qw + (size_t)(k0 + 8 * h + j) * NP + np0 + hw;
                qrow[j] = rp[sub * 8];
            }
            f16x8 b;
#pragma unroll
            for (int j = 0; j < 8; ++j) {
                int qn = (qrow[j] >> sh) & 15;
                float wf = (float)qn * sv[sub] - zs[sub];
                b[j] = (_Float16)wf;
            }
            acc[0][sub] = __builtin_amdgcn_mfma_f32_16x16x32_f16(a0, b, acc[0][sub], 0, 0, 0);
            acc[1][sub] = __builtin_amdgcn_mfma_f32_16x16x32_f16(a1, b, acc[1][sub], 0, 0, 0);
        }
    }

    // write per-wave partial C into LDS
    // C/D layout (16x16x32): row = h*4 + r, col = c
#pragma unroll
    for (int mb = 0; mb < 2; ++mb)
#pragma unroll
        for (int sub = 0; sub < 4; ++sub)
#pragma unroll
            for (int r = 0; r < 4; ++r)
                red[w * 2048 + (mb * 16 + h * 4 + r) * 64 + sub * 16 + c] = acc[mb][sub][r];

    __syncthreads();

    // cross-wave reduce + bias + store
#pragma unroll
    for (int i = 0; i < 4; ++i) {
        int e = i * 512 + tid;       // 0..2047
        float s = 0.f;
#pragma unroll
        for (int ww = 0; ww < 8; ++ww) s += red[ww * 2048 + e];
        int m = e >> 6;
        int n = n0 + (e & 63);
        out[(size_t)m * NOUT + n] = s + bias[n];
    }
}

extern "C" void kernel_launch(void* const* d_in, const int* in_sizes, int n_in,
                              void* d_out, int out_size, void* d_ws, size_t ws_size,
                              hipStream_t stream) {
    const float* x       = (const float*)d_in[0];
    const int*   qweight = (const int*)d_in[1];
    const float* scales  = (const float*)d_in[2];
    const int*   qzeros  = (const int*)d_in[3];
    const float* bias    = (const float*)d_in[4];
    // d_in[5]=blocksize(128), d_in[6]=n_dim(32000): compile-time constants here

    _Float16* aws = (_Float16*)d_ws;   // 256 KB A-fragment scratch
    float* out = (float*)d_out;

    prep_a_kernel<<<64, 256, 0, stream>>>(x, aws);
    q4gemm_kernel<<<500, 512, 0, stream>>>(qweight, scales, qzeros, bias, aws, out);
}

// Round 2
// 50.156 us; speedup vs baseline: 1.1703x; 1.1703x over previous
//
#include <hip/hip_runtime.h>
#include <hip/hip_bf16.h>

// int4-dequant GEMM, M=32 (last token), K=4096, N=32000 (of 32064 padded).
// qweight [K][16032] int32 (one byte/word: lo nibble = even col, hi = odd col)
// w[k][n] = (q - z) * s, group g = k/128.
//
// f16 MFMA (16x16x32), fp32 accumulate. A pre-packed to fragment layout in
// d_ws (k-bijection kappa(h,j)=8h+j, shared by A and B so HW k-order cancels).
// Column-to-lane remap: lane c owns physical cols 4c+s (s=sub 0..3), so each
// lane loads ONE dwordx2 per row covering all 4 sub-tiles -> 8 coalesced
// loads/t (vs 32 scattered), zero duplication. Dequant in packed f16 via the
// 0x6400 nibble-bias trick: (f16(1024+q) - f16(1024+z)) * f16(s), q-z exact.
// 2-deep register double-buffer prefetches next k-step's rows under MFMA.

typedef _Float16 f16x8 __attribute__((ext_vector_type(8)));
typedef _Float16 f16x2 __attribute__((ext_vector_type(2)));
typedef float f32x4 __attribute__((ext_vector_type(4)));

#define K_DIM 4096
#define NP 16032       // packed words per qweight/qzeros row
#define NSC 32064      // scales row pitch
#define NOUT 32000
#define S_LEN 64
#define QROWB ((size_t)NP * 4)          // bytes per qweight row
#define QSTEP (32u * (uint32_t)NP * 4u) // byte advance per k-step (32 rows)

// ---- pre-kernel: pack x[:,63,:] (f32) into A fragments (f16) ----
// aws[(kstep*2 + mblk)*64 + lane][j]: A[m][k], m = mblk*16 + (lane&15),
// k = kstep*32 + 8*(lane>>4) + j
__global__ void prep_a_kernel(const float* __restrict__ x,
                              _Float16* __restrict__ aws) {
    int tid = blockIdx.x * 256 + threadIdx.x;   // 0..16383
    int l = tid & 63;
    int mblk = (tid >> 6) & 1;
    int ks = tid >> 7;                          // kstep 0..127
    int m = mblk * 16 + (l & 15);
    int kbase = ks * 32 + 8 * (l >> 4);
    const float* xp = x + (size_t)m * S_LEN * K_DIM + (size_t)(S_LEN - 1) * K_DIM + kbase;
    _Float16* op = aws + (size_t)tid * 8;
#pragma unroll
    for (int j = 0; j < 8; ++j) op[j] = (_Float16)xp[j];
}

__device__ __forceinline__ int f16pk(int w0, int w1, int sh2) {
    int e0 = (w0 >> sh2) & 15;
    int e1 = (w1 >> sh2) & 15;
    return e0 | (e1 << 16) | 0x64006400;
}

// ---- main kernel ----
__global__ __launch_bounds__(512, 4)
void q4gemm_kernel(const int* __restrict__ qw,
                   const float* __restrict__ scales,
                   const int* __restrict__ qzeros,
                   const float* __restrict__ bias,
                   const _Float16* __restrict__ aws,
                   float* __restrict__ out) {
    __shared__ float red[8 * 2048];   // 64 KB: per-wave partial C tiles

    const int tid = threadIdx.x;
    const int w = tid >> 6;          // wave 0..7 (K-chunk owner)
    const int l = tid & 63;
    const int h = l >> 4;            // k lane-group 0..3 (rows 8h+j)
    const int c = l & 15;            // lane's column group: phys cols 4c+s
    const int n0 = blockIdx.x * 64;
    const int np0 = n0 >> 1;

    const char* qwb = (const char*)qw;
    // byte offset of row (w*512 + 8h), words np0+2c
    uint32_t qoff = (uint32_t)((w * 512 + 8 * h) * (size_t)NP + np0 + 2 * c) * 4u;

    f32x4 acc0[4] = {};   // mblk 0, sub 0..3
    f32x4 acc1[4] = {};   // mblk 1
    f16x2 vz[4], vs[4];   // per-group packed (1024+z) and scale, per sub

    int2 qa[8], qb[8];

#define QLD(buf)                                                              \
    do {                                                                      \
        _Pragma("unroll") for (int j = 0; j < 8; ++j)                         \
            buf[j] = *(const int2*)(qwb + qoff + (size_t)j * QROWB);          \
        qoff += QSTEP;                                                        \
    } while (0)

#define GRPUPD(g)                                                             \
    do {                                                                      \
        f32x4 sc4 = *(const f32x4*)(scales + (size_t)(g) * NSC + n0 + 4 * c); \
        int2 zw = *(const int2*)(qzeros + (size_t)(g) * NP + np0 + 2 * c);    \
        _Pragma("unroll") for (int s = 0; s < 4; ++s) {                       \
            int zword = (s < 2) ? zw.x : zw.y;                                \
            int z = (zword >> ((s & 1) * 4)) & 15;                            \
            int zp = z | (z << 16) | 0x64006400;                              \
            vz[s] = __builtin_bit_cast(f16x2, zp);                            \
            _Float16 sh_ = (_Float16)sc4[s];                                  \
            f16x2 sp = {sh_, sh_};                                            \
            vs[s] = sp;                                                       \
        }                                                                     \
    } while (0)

#define COMPUTE(buf, ksg)                                                     \
    do {                                                                      \
        f16x8 a0 = *(const f16x8*)(aws + ((size_t)((ksg) * 2 + 0) * 64 + l) * 8); \
        f16x8 a1 = *(const f16x8*)(aws + ((size_t)((ksg) * 2 + 1) * 64 + l) * 8); \
        _Pragma("unroll") for (int s = 0; s < 4; ++s) {                       \
            const int sh2 = (s & 1) * 4;                                      \
            int4 bi;                                                          \
            _Pragma("unroll") for (int p = 0; p < 4; ++p) {                   \
                int w0 = (s < 2) ? buf[2 * p].x : buf[2 * p].y;               \
                int w1 = (s < 2) ? buf[2 * p + 1].x : buf[2 * p + 1].y;       \
                f16x2 vq = __builtin_bit_cast(f16x2, f16pk(w0, w1, sh2));     \
                f16x2 r = (vq - vz[s]) * vs[s];                               \
                bi[p] = __builtin_bit_cast(int, r);                           \
            }                                                                 \
            f16x8 b = __builtin_bit_cast(f16x8, bi);                          \
            acc0[s] = __builtin_amdgcn_mfma_f32_16x16x32_f16(a0, b, acc0[s], 0, 0, 0); \
            acc1[s] = __builtin_amdgcn_mfma_f32_16x16x32_f16(a1, b, acc1[s], 0, 0, 0); \
        }                                                                     \
    } while (0)

    QLD(qa);   // t=0
#pragma unroll
    for (int tt = 0; tt < 8; ++tt) {
        const int t0 = 2 * tt;
        QLD(qb);                       // prefetch t0+1
        if ((tt & 1) == 0) GRPUPD(w * 4 + tt / 2);
        COMPUTE(qa, w * 16 + t0);
        if (tt < 7) QLD(qa);           // prefetch t0+2
        COMPUTE(qb, w * 16 + t0 + 1);
    }

    // per-wave partial C -> LDS. C/D: row = h*4 + r, phys col = 4c + s
#pragma unroll
    for (int s = 0; s < 4; ++s)
#pragma unroll
        for (int r = 0; r < 4; ++r) {
            red[w * 2048 + (h * 4 + r) * 64 + 4 * c + s] = acc0[s][r];
            red[w * 2048 + (16 + h * 4 + r) * 64 + 4 * c + s] = acc1[s][r];
        }

    __syncthreads();

    // cross-wave reduce + bias + store
#pragma unroll
    for (int i = 0; i < 4; ++i) {
        int e = i * 512 + tid;       // 0..2047
        float sum = 0.f;
#pragma unroll
        for (int ww = 0; ww < 8; ++ww) sum += red[ww * 2048 + e];
        int m = e >> 6;
        int n = n0 + (e & 63);
        out[(size_t)m * NOUT + n] = sum + bias[n];
    }
}

extern "C" void kernel_launch(void* const* d_in, const int* in_sizes, int n_in,
                              void* d_out, int out_size, void* d_ws, size_t ws_size,
                              hipStream_t stream) {
    const float* x       = (const float*)d_in[0];
    const int*   qweight = (const int*)d_in[1];
    const float* scales  = (const float*)d_in[2];
    const int*   qzeros  = (const int*)d_in[3];
    const float* bias    = (const float*)d_in[4];

    _Float16* aws = (_Float16*)d_ws;   // 256 KB A-fragment scratch
    float* out = (float*)d_out;

    prep_a_kernel<<<64, 256, 0, stream>>>(x, aws);
    q4gemm_kernel<<<500, 512, 0, stream>>>(qweight, scales, qzeros, bias, aws, out);
}